// Round 1
// baseline (124.408 us; speedup 1.0000x reference)
//
#include <hip/hip_runtime.h>
#include <math.h>

#define HH 768
#define NB 8
#define LL 256
#define MM 128
#define NROW1 (NB*MM)        // 1024 dns rows
#define NROW2 (NB*LL)        // 2048 text rows
#define NROWS (NROW1+NROW2)  // 3072
#define NCB 12               // 768/64 column blocks

// ---------------------------------------------------------------------------
// Fused GEMM + tanh + dot kernel.
// Computes partial[row][colblock] = sum_{o in colblock} tanh(X[row,:]·W[o,:]) * wvec[o]
// X: [nrows][768] row-major, W: [768][768] row-major (o-major), wvec: [768].
// Tile: 64 rows x 64 cols, BK=16, 256 threads, 4x4 micro-tile per thread.
// LDS stored transposed [k][r] so fragment reads are ds_read_b128.
// ---------------------------------------------------------------------------
__global__ __launch_bounds__(256) void score_kernel(
    const float* __restrict__ X, const float* __restrict__ W,
    const float* __restrict__ wvec, float* __restrict__ partial, int row_base)
{
    __shared__ __align__(16) float As[16][64];
    __shared__ __align__(16) float Bs[16][64];
    const int lid = threadIdx.x;
    const int tx = lid & 15;       // col group (4 cols)
    const int ty = lid >> 4;       // row group (4 rows)
    const int row0 = blockIdx.x * 64;
    const int col0 = blockIdx.y * 64;

    const int lr = lid >> 2;           // 0..63 (tile row for staging)
    const int lk = (lid & 3) * 4;      // 0,4,8,12 (k offset for staging)
    const float* Xp = X + (size_t)(row0 + lr) * HH + lk;
    const float* Wp = W + (size_t)(col0 + lr) * HH + lk;

    float acc[4][4] = {};

    for (int k0 = 0; k0 < HH; k0 += 16) {
        float4 a  = *reinterpret_cast<const float4*>(Xp + k0);
        float4 bv = *reinterpret_cast<const float4*>(Wp + k0);
        As[lk+0][lr] = a.x;  As[lk+1][lr] = a.y;  As[lk+2][lr] = a.z;  As[lk+3][lr] = a.w;
        Bs[lk+0][lr] = bv.x; Bs[lk+1][lr] = bv.y; Bs[lk+2][lr] = bv.z; Bs[lk+3][lr] = bv.w;
        __syncthreads();
        #pragma unroll
        for (int k = 0; k < 16; ++k) {
            float4 av = *reinterpret_cast<const float4*>(&As[k][ty * 4]);
            float4 bw = *reinterpret_cast<const float4*>(&Bs[k][tx * 4]);
            float ar[4] = {av.x, av.y, av.z, av.w};
            float br[4] = {bw.x, bw.y, bw.z, bw.w};
            #pragma unroll
            for (int i = 0; i < 4; ++i)
                #pragma unroll
                for (int j = 0; j < 4; ++j)
                    acc[i][j] = fmaf(ar[i], br[j], acc[i][j]);
        }
        __syncthreads();
    }

    // epilogue: tanh, weight, reduce across the 16 tx groups (same 4 rows)
    float wv[4];
    #pragma unroll
    for (int j = 0; j < 4; ++j) wv[j] = wvec[col0 + tx * 4 + j];

    #pragma unroll
    for (int i = 0; i < 4; ++i) {
        float s = 0.f;
        #pragma unroll
        for (int j = 0; j < 4; ++j) s += tanhf(acc[i][j]) * wv[j];
        #pragma unroll
        for (int d = 1; d < 16; d <<= 1) s += __shfl_xor(s, d);
        if (tx == 0)
            partial[(size_t)(row_base + row0 + ty * 4 + i) * NCB + blockIdx.y] = s;
    }
}

// ---------------------------------------------------------------------------
// Reduce the 12 column-block partials per row, then per-batch softmax.
// blocks 0..7  -> p1[b][0..127]  (rows b*128 .. in part1 region)
// blocks 8..15 -> p2[b][0..255]  (rows NROW1 + b*256 ..)
// ---------------------------------------------------------------------------
__global__ __launch_bounds__(256) void softmax_kernel(
    const float* __restrict__ partial, float* __restrict__ p1, float* __restrict__ p2)
{
    const int which = blockIdx.x >> 3;
    const int b = blockIdx.x & 7;
    const int n = which ? 256 : 128;
    const int row_base = which ? (NROW1 + b * 256) : (b * 128);
    float* dst = which ? (p2 + b * 256) : (p1 + b * 128);

    const int t = threadIdx.x;
    float v = -INFINITY;
    if (t < n) {
        float vv = 0.f;
        const float* pr = partial + (size_t)(row_base + t) * NCB;
        #pragma unroll
        for (int c = 0; c < NCB; ++c) vv += pr[c];
        v = vv;
    }

    __shared__ float sbuf[4];
    float m = v;
    #pragma unroll
    for (int d = 1; d < 64; d <<= 1) m = fmaxf(m, __shfl_xor(m, d));
    if ((t & 63) == 0) sbuf[t >> 6] = m;
    __syncthreads();
    m = fmaxf(fmaxf(sbuf[0], sbuf[1]), fmaxf(sbuf[2], sbuf[3]));
    __syncthreads();

    float e = (t < n) ? expf(v - m) : 0.f;
    float s = e;
    #pragma unroll
    for (int d = 1; d < 64; d <<= 1) s += __shfl_xor(s, d);
    if ((t & 63) == 0) sbuf[t >> 6] = s;
    __syncthreads();
    s = sbuf[0] + sbuf[1] + sbuf[2] + sbuf[3];

    if (t < n) dst[t] = e / s;
}

// ---------------------------------------------------------------------------
// Per-batch weighted sums: vd[b,h] = sum_m p1[b,m] dns[b,m,h]
//                          vt[b,h] = sum_j p2[b,j] text[b,j,h]
// grid (8, 6): 128 h per block, 2 slices over the reduction axis.
// ---------------------------------------------------------------------------
__global__ __launch_bounds__(256) void vec_kernel(
    const float* __restrict__ text, const float* __restrict__ dns,
    const float* __restrict__ p1, const float* __restrict__ p2,
    float* __restrict__ vd, float* __restrict__ vt)
{
    const int b = blockIdx.x;
    const int h = blockIdx.y * 128 + (threadIdx.x & 127);
    const int slice = threadIdx.x >> 7;   // 0 or 1
    const int t = threadIdx.x;

    float sd = 0.f;
    #pragma unroll 4
    for (int m = slice * 64; m < slice * 64 + 64; ++m)
        sd = fmaf(p1[b * 128 + m], dns[(size_t)(b * 128 + m) * HH + h], sd);

    float st = 0.f;
    #pragma unroll 4
    for (int j = slice * 128; j < slice * 128 + 128; ++j)
        st = fmaf(p2[b * 256 + j], text[(size_t)(b * 256 + j) * HH + h], st);

    __shared__ float bd[256], bt[256];
    bd[t] = sd; bt[t] = st;
    __syncthreads();
    if (slice == 0) {
        vd[b * HH + h] = bd[t] + bd[t + 128];
        vt[b * HH + h] = bt[t] + bt[t + 128];
    }
}

// ---------------------------------------------------------------------------
// Broadcast: out[0..n) = att_text (vt broadcast over L), out[n..2n) = att_dns.
// ---------------------------------------------------------------------------
__global__ __launch_bounds__(256) void bcast_kernel(
    const float* __restrict__ vt, const float* __restrict__ vd, float4* __restrict__ out)
{
    const int n4 = NB * LL * HH / 4;          // 393216 per output
    const int H4 = HH / 4;                    // 192
    const int LH4 = LL * H4;                  // 49152
    const float4* vt4 = reinterpret_cast<const float4*>(vt);
    const float4* vd4 = reinterpret_cast<const float4*>(vd);
    int i = blockIdx.x * blockDim.x + threadIdx.x;
    for (; i < 2 * n4; i += gridDim.x * blockDim.x) {
        const int which = (i >= n4);
        const int q = which ? (i - n4) : i;
        const int b = q / LH4;
        const int h4 = q % H4;
        const float4* src = which ? vd4 : vt4;
        out[i] = src[b * H4 + h4];
    }
}

extern "C" void kernel_launch(void* const* d_in, const int* in_sizes, int n_in,
                              void* d_out, int out_size, void* d_ws, size_t ws_size,
                              hipStream_t stream) {
    const float* text   = (const float*)d_in[0];   // (8,256,768)
    const float* dns    = (const float*)d_in[1];   // (8,128,768)
    const float* W_d1   = (const float*)d_in[4];   // (768,768)
    const float* w_att1 = (const float*)d_in[5];   // (1536,)
    const float* W_t2   = (const float*)d_in[9];   // (768,768)
    const float* w_att2 = (const float*)d_in[10];  // (1536,)

    float* ws      = (float*)d_ws;
    float* partial = ws;              // 3072*12 = 36864
    float* p1      = ws + 36864;      // 1024
    float* p2      = ws + 37888;      // 2048
    float* vd      = ws + 39936;      // 6144  (att_dns vec)
    float* vt      = ws + 46080;      // 6144  (att_text vec)
    float* out     = (float*)d_out;

    // v1 rows (dns through W_d1, weighted by w_att1[H:])
    score_kernel<<<dim3(NROW1 / 64, NCB), 256, 0, stream>>>(dns, W_d1, w_att1 + HH, partial, 0);
    // v2 rows (text through W_t2, weighted by w_att2[H:])
    score_kernel<<<dim3(NROW2 / 64, NCB), 256, 0, stream>>>(text, W_t2, w_att2 + HH, partial, NROW1);
    softmax_kernel<<<16, 256, 0, stream>>>(partial, p1, p2);
    vec_kernel<<<dim3(8, 6), 256, 0, stream>>>(text, dns, p1, p2, vd, vt);
    bcast_kernel<<<3072, 256, 0, stream>>>(vt, vd, (float4*)out);
}

// Round 3
// 45.234 us; speedup vs baseline: 2.7503x; 2.7503x over previous
//
#include <hip/hip_runtime.h>
#include <hip/hip_bf16.h>
#include <math.h>

#define HH 768
#define NB 8
#define LL 256
#define MM 128
#define NROW1 (NB*MM)        // 1024 dns rows
#define NROW2 (NB*LL)        // 2048 text rows
#define NROWS (NROW1+NROW2)  // 3072
#define NCB 12               // 768/64 column blocks

typedef __attribute__((ext_vector_type(8))) short  bf16x8;
typedef __attribute__((ext_vector_type(4))) float  f32x4;
typedef __attribute__((ext_vector_type(4))) unsigned int u32x4;

static __device__ __forceinline__ unsigned int pkbf2(float a, float b) {
    __hip_bfloat162 h = __float22bfloat162_rn(make_float2(a, b));
    unsigned int u; __builtin_memcpy(&u, &h, 4); return u;
}

static __device__ __forceinline__ float fast_tanh(float x) {
    float e = __expf(2.0f * x);
    return 1.0f - 2.0f * __builtin_amdgcn_rcpf(e + 1.0f);
}

// ---------------------------------------------------------------------------
// Fused bf16-MFMA GEMM + tanh + dot. Covers BOTH score GEMMs.
// partial[row][cb] = sum_{o in colblock cb} tanh(X[row,:]·W[o,:]) * wvec[o]
// Tile 64x64, BK=64, 256 threads. Wave w owns rows [w*16, w*16+16) x ALL 64
// cols (1 A-frag x 4 B-frags) -- so the in-wave 16-lane shuffle reduces the
// COMPLETE column sum (round-2 bug: two waves shared rows and clobbered each
// other's half-sums in partial).
// ---------------------------------------------------------------------------
__global__ __launch_bounds__(256) void score_mfma(
    const float* __restrict__ text, const float* __restrict__ dns,
    const float* __restrict__ Wd1, const float* __restrict__ Wt2,
    const float* __restrict__ wv1, const float* __restrict__ wv2,
    float* __restrict__ partial)
{
    __shared__ __align__(16) unsigned short As[64][72];
    __shared__ __align__(16) unsigned short Bs[64][72];

    const int t = threadIdx.x;
    const int row0 = blockIdx.x * 64;
    const int col0 = blockIdx.y * 64;

    const float* X; const float* W; const float* wv; int rbase;
    if (row0 < NROW1) { X = dns;  rbase = row0;         W = Wd1; wv = wv1; }
    else              { X = text; rbase = row0 - NROW1; W = Wt2; wv = wv2; }

    const int sr = t >> 2;        // staging row 0..63
    const int c4 = t & 3;         // k-subgroup
    const float* xp = X + (size_t)(rbase + sr) * HH;
    const float* wp = W + (size_t)(col0 + sr) * HH;

    const int l  = t & 63;
    const int w  = t >> 6;
    const int wr = w * 16;        // this wave's 16 output rows
    const int lc = l & 15;
    const int lk = (l >> 4) * 8;

    f32x4 acc[4] = {};
    float4 rA[4], rB[4], nA[4], nB[4];

    auto STAGE = [&]() {
        #pragma unroll
        for (int g = 0; g < 2; ++g) {
            const int k = c4 * 8 + g * 32;
            u32x4 pa, pb;
            pa[0] = pkbf2(rA[g*2].x,   rA[g*2].y);
            pa[1] = pkbf2(rA[g*2].z,   rA[g*2].w);
            pa[2] = pkbf2(rA[g*2+1].x, rA[g*2+1].y);
            pa[3] = pkbf2(rA[g*2+1].z, rA[g*2+1].w);
            pb[0] = pkbf2(rB[g*2].x,   rB[g*2].y);
            pb[1] = pkbf2(rB[g*2].z,   rB[g*2].w);
            pb[2] = pkbf2(rB[g*2+1].x, rB[g*2+1].y);
            pb[3] = pkbf2(rB[g*2+1].z, rB[g*2+1].w);
            *reinterpret_cast<u32x4*>(&As[sr][k]) = pa;
            *reinterpret_cast<u32x4*>(&Bs[sr][k]) = pb;
        }
    };

    auto MFMA_TILE = [&]() {
        #pragma unroll
        for (int kk = 0; kk < 2; ++kk) {
            const int ko = kk * 32 + lk;
            bf16x8 a = *reinterpret_cast<const bf16x8*>(&As[wr + lc][ko]);
            #pragma unroll
            for (int n = 0; n < 4; ++n) {
                bf16x8 b = *reinterpret_cast<const bf16x8*>(&Bs[n*16 + lc][ko]);
                acc[n] = __builtin_amdgcn_mfma_f32_16x16x32_bf16(a, b, acc[n], 0, 0, 0);
            }
        }
    };

    // prologue loads (k0 = 0)
    #pragma unroll
    for (int g = 0; g < 2; ++g) {
        const int k = c4 * 8 + g * 32;
        rA[g*2+0] = *(const float4*)(xp + k);
        rA[g*2+1] = *(const float4*)(xp + k + 4);
        rB[g*2+0] = *(const float4*)(wp + k);
        rB[g*2+1] = *(const float4*)(wp + k + 4);
    }

    #pragma unroll 1
    for (int k0 = 0; k0 < HH - 64; k0 += 64) {
        STAGE();
        __syncthreads();
        // prefetch next K-tile (hide HBM under MFMA)
        #pragma unroll
        for (int g = 0; g < 2; ++g) {
            const int k = k0 + 64 + c4 * 8 + g * 32;
            nA[g*2+0] = *(const float4*)(xp + k);
            nA[g*2+1] = *(const float4*)(xp + k + 4);
            nB[g*2+0] = *(const float4*)(wp + k);
            nB[g*2+1] = *(const float4*)(wp + k + 4);
        }
        MFMA_TILE();
        __syncthreads();
        #pragma unroll
        for (int q = 0; q < 4; ++q) { rA[q] = nA[q]; rB[q] = nB[q]; }
    }
    STAGE();
    __syncthreads();
    MFMA_TILE();

    // epilogue: tanh * wvec over all 64 cols (4 frags), 16-lane reduce
    float wvn[4];
    #pragma unroll
    for (int n = 0; n < 4; ++n) wvn[n] = wv[col0 + n*16 + lc];
    #pragma unroll
    for (int i = 0; i < 4; ++i) {
        float s = 0.f;
        #pragma unroll
        for (int n = 0; n < 4; ++n) s += fast_tanh(acc[n][i]) * wvn[n];
        s += __shfl_xor(s, 1);
        s += __shfl_xor(s, 2);
        s += __shfl_xor(s, 4);
        s += __shfl_xor(s, 8);
        if (lc == 0)
            partial[(size_t)(row0 + wr + (l >> 4)*4 + i) * NCB + blockIdx.y] = s;
    }
}

// ---------------------------------------------------------------------------
// Per (batch, h-chunk): reduce partials -> softmax (both) -> weighted sums.
// ---------------------------------------------------------------------------
__global__ __launch_bounds__(256) void finish_kernel(
    const float* __restrict__ text, const float* __restrict__ dns,
    const float* __restrict__ partial, float* __restrict__ vd, float* __restrict__ vt)
{
    const int b = blockIdx.x, hc = blockIdx.y;
    const int t = threadIdx.x;
    __shared__ float p1s[128], p2s[256], red[8], bd[256], bt[256];

    if (t < 128) {
        const float* pr = partial + (size_t)(b * MM + t) * NCB;
        float s = 0.f;
        #pragma unroll
        for (int c = 0; c < NCB; ++c) s += pr[c];
        p1s[t] = s;
    }
    {
        const float* pr = partial + (size_t)(NROW1 + b * LL + t) * NCB;
        float s = 0.f;
        #pragma unroll
        for (int c = 0; c < NCB; ++c) s += pr[c];
        p2s[t] = s;
    }
    __syncthreads();

    float x1 = (t < 128) ? p1s[t] : -1e30f;
    float m1 = x1;
    #pragma unroll
    for (int d = 1; d < 64; d <<= 1) m1 = fmaxf(m1, __shfl_xor(m1, d));
    if ((t & 63) == 0) red[t >> 6] = m1;
    float x2 = p2s[t];
    float m2 = x2;
    #pragma unroll
    for (int d = 1; d < 64; d <<= 1) m2 = fmaxf(m2, __shfl_xor(m2, d));
    if ((t & 63) == 0) red[4 + (t >> 6)] = m2;
    __syncthreads();
    m1 = fmaxf(fmaxf(red[0], red[1]), fmaxf(red[2], red[3]));
    m2 = fmaxf(fmaxf(red[4], red[5]), fmaxf(red[6], red[7]));

    float e1 = (t < 128) ? __expf(x1 - m1) : 0.f;
    float e2 = __expf(x2 - m2);
    __syncthreads();
    float s1 = e1, s2 = e2;
    #pragma unroll
    for (int d = 1; d < 64; d <<= 1) { s1 += __shfl_xor(s1, d); s2 += __shfl_xor(s2, d); }
    if ((t & 63) == 0) { red[t >> 6] = s1; red[4 + (t >> 6)] = s2; }
    __syncthreads();
    s1 = red[0] + red[1] + red[2] + red[3];
    s2 = red[4] + red[5] + red[6] + red[7];
    if (t < 128) p1s[t] = e1 / s1;
    p2s[t] = e2 / s2;
    __syncthreads();

    const int h = hc * 128 + (t & 127);
    const int slice = t >> 7;
    float sd = 0.f;
    #pragma unroll 4
    for (int m = slice * 64; m < slice * 64 + 64; ++m)
        sd = fmaf(p1s[m], dns[(size_t)(b * MM + m) * HH + h], sd);
    float st = 0.f;
    #pragma unroll 4
    for (int j = slice * 128; j < slice * 128 + 128; ++j)
        st = fmaf(p2s[j], text[(size_t)(b * LL + j) * HH + h], st);
    bd[t] = sd; bt[t] = st;
    __syncthreads();
    if (slice == 0) {
        vd[b * HH + h] = bd[t] + bd[t + 128];
        vt[b * HH + h] = bt[t] + bt[t + 128];
    }
}

// ---------------------------------------------------------------------------
// Broadcast: out[0..n) = att_text (vt over L), out[n..2n) = att_dns (vd).
// ---------------------------------------------------------------------------
__global__ __launch_bounds__(256) void bcast_kernel(
    const float* __restrict__ vt, const float* __restrict__ vd, float4* __restrict__ out)
{
    const int n4 = NB * LL * HH / 4;          // 393216 per output
    const int H4 = HH / 4;                    // 192
    const int LH4 = LL * H4;                  // 49152
    const float4* vt4 = reinterpret_cast<const float4*>(vt);
    const float4* vd4 = reinterpret_cast<const float4*>(vd);
    int i = blockIdx.x * blockDim.x + threadIdx.x;
    for (; i < 2 * n4; i += gridDim.x * blockDim.x) {
        const int which = (i >= n4);
        const int q = which ? (i - n4) : i;
        const int b = q / LH4;
        const int h4 = q % H4;
        const float4* src = which ? vd4 : vt4;
        out[i] = src[b * H4 + h4];
    }
}

extern "C" void kernel_launch(void* const* d_in, const int* in_sizes, int n_in,
                              void* d_out, int out_size, void* d_ws, size_t ws_size,
                              hipStream_t stream) {
    const float* text   = (const float*)d_in[0];   // (8,256,768)
    const float* dns    = (const float*)d_in[1];   // (8,128,768)
    const float* W_d1   = (const float*)d_in[4];   // (768,768)
    const float* w_att1 = (const float*)d_in[5];   // (1536,)
    const float* W_t2   = (const float*)d_in[9];   // (768,768)
    const float* w_att2 = (const float*)d_in[10];  // (1536,)

    float* ws      = (float*)d_ws;
    float* partial = ws;                       // 3072*12 = 36864
    float* vd      = ws + 36864;               // 6144
    float* vt      = ws + 43008;               // 6144
    float* out     = (float*)d_out;

    score_mfma<<<dim3(NROWS / 64, NCB), 256, 0, stream>>>(
        text, dns, W_d1, W_t2, w_att1 + HH, w_att2 + HH, partial);
    finish_kernel<<<dim3(NB, 6), 256, 0, stream>>>(text, dns, partial, vd, vt);
    bcast_kernel<<<3072, 256, 0, stream>>>(vt, vd, (float4*)out);
}